// Round 3
// baseline (120.201 us; speedup 1.0000x reference)
//
#include <hip/hip_runtime.h>
#include <hip/hip_fp16.h>

#define D 128
#define EPS 1e-12f
#define FP8_SCALE 64.0f
#define FP8_INV_SCALE 0.015625f

typedef float v2f __attribute__((ext_vector_type(2)));
typedef float v4f __attribute__((ext_vector_type(4)));   // native vector: OK for nontemporal builtins

// ---------- fp8-e4m3 table path ----------

// Pass 1 (one dispatch):
//   rows [0, N):    L1-normalize z row -> fp8 e4m3 (*64 scale), 128B/row
//   rows [N, N+R):  cast rel row fp32 -> fp16, 256B/row
// 2 rows per wave: lane = 32*rh + sub, 16B loads/lane, half-wave
// butterfly reduce (masks <32 stay within each 32-lane half).
__global__ void build_tables_kernel(const float* __restrict__ z,
                                    const float* __restrict__ rel,
                                    unsigned char* __restrict__ zn,
                                    __half* __restrict__ relh,
                                    int N, int R) {
    int wave = threadIdx.x >> 6;
    int lane = threadIdx.x & 63;
    int rh   = lane >> 5;              // which of the wave's 2 rows
    int sub  = lane & 31;              // float4 index within the row
    int row  = blockIdx.x * ((blockDim.x >> 6) * 2) + wave * 2 + rh;

    if (row < N) {
        const v4f* zp = (const v4f*)(z + (size_t)row * D);
        v4f v = __builtin_nontemporal_load(zp + sub);      // z read once: don't pollute caches
        float s = fabsf(v.x) + fabsf(v.y) + fabsf(v.z) + fabsf(v.w);
        #pragma unroll
        for (int m = 16; m >= 1; m >>= 1)
            s += __shfl_xor(s, m, 64);                     // 5-step, within 32-lane half
        float f = FP8_SCALE / fmaxf(s, EPS);
        unsigned int p = __builtin_amdgcn_cvt_pk_fp8_f32(v.x * f, v.y * f, 0, false);
        p = __builtin_amdgcn_cvt_pk_fp8_f32(v.z * f, v.w * f, p, true);
        ((unsigned int*)(zn + (size_t)row * D))[sub] = p;  // 32 lanes x 4B = 128B row
    } else {
        int rr = row - N;
        if (rr < R) {
            const float4* rp = (const float4*)(rel + (size_t)rr * D);
            float4 v = rp[sub];
            float2 w;
            ((__half2*)&w)[0] = __floats2half2_rn(v.x, v.y);
            ((__half2*)&w)[1] = __floats2half2_rn(v.z, v.w);
            ((float2*)(relh + (size_t)rr * D))[sub] = w;   // 32 lanes x 8B = 256B row
        }
    }
}

// Pass 2: 4 lanes per edge (16 edges/wave).
// Per lane: 2x uint4 (32 fp8) per z row, 4x uint4 (32 fp16) of the rel row.
// 8 independent gather loads in flight per thread (2x the MLP of the 8-lane
// version), fewer VMEM instructions and shuffles per edge.
__global__ void transe_score_fp8_kernel(const unsigned char* __restrict__ zn,
                                        const __half* __restrict__ relh,
                                        const int* __restrict__ eidx,   // [2,E]
                                        const int* __restrict__ etype,  // [E]
                                        float* __restrict__ out, int E) {
    int gtid = blockIdx.x * blockDim.x + threadIdx.x;
    int e = gtid >> 2;
    int lane4 = threadIdx.x & 3;
    if (e >= E) return;

    int h = __builtin_nontemporal_load(eidx + e);
    int t = __builtin_nontemporal_load(eidx + E + e);
    int r = __builtin_nontemporal_load(etype + e);

    const uint4* hp = (const uint4*)(zn + (size_t)h * D);
    const uint4* tp = (const uint4*)(zn + (size_t)t * D);
    const uint4* rp = (const uint4*)(relh + (size_t)r * D);

    uint4 hv0 = hp[lane4 * 2];
    uint4 hv1 = hp[lane4 * 2 + 1];
    uint4 tv0 = tp[lane4 * 2];
    uint4 tv1 = tp[lane4 * 2 + 1];
    uint4 rv0 = rp[lane4 * 4];
    uint4 rv1 = rp[lane4 * 4 + 1];
    uint4 rv2 = rp[lane4 * 4 + 2];
    uint4 rv3 = rp[lane4 * 4 + 3];

    unsigned int hw[8] = {hv0.x, hv0.y, hv0.z, hv0.w, hv1.x, hv1.y, hv1.z, hv1.w};
    unsigned int tw[8] = {tv0.x, tv0.y, tv0.z, tv0.w, tv1.x, tv1.y, tv1.z, tv1.w};
    unsigned int rw[16] = {rv0.x, rv0.y, rv0.z, rv0.w, rv1.x, rv1.y, rv1.z, rv1.w,
                           rv2.x, rv2.y, rv2.z, rv2.w, rv3.x, rv3.y, rv3.z, rv3.w};

    float s = 0.0f;
    #pragma unroll
    for (int k = 0; k < 8; ++k) {
        v2f h0 = __builtin_amdgcn_cvt_pk_f32_fp8(hw[k], false);
        v2f h1 = __builtin_amdgcn_cvt_pk_f32_fp8(hw[k], true);
        v2f t0 = __builtin_amdgcn_cvt_pk_f32_fp8(tw[k], false);
        v2f t1 = __builtin_amdgcn_cvt_pk_f32_fp8(tw[k], true);
        float2 r0 = __half22float2(*(const __half2*)&rw[2 * k]);
        float2 r1 = __half22float2(*(const __half2*)&rw[2 * k + 1]);
        s += fabsf(fmaf(h0.x - t0.x, FP8_INV_SCALE, r0.x));
        s += fabsf(fmaf(h0.y - t0.y, FP8_INV_SCALE, r0.y));
        s += fabsf(fmaf(h1.x - t1.x, FP8_INV_SCALE, r1.x));
        s += fabsf(fmaf(h1.y - t1.y, FP8_INV_SCALE, r1.y));
    }
    s += __shfl_xor(s, 1, 64);
    s += __shfl_xor(s, 2, 64);
    if (lane4 == 0) __builtin_nontemporal_store(-s, out + e);
}

// ---------- fp16 fallback path (round-2, proven) ----------

__global__ void normalize_to_half_kernel(const float* __restrict__ z,
                                         __half* __restrict__ zn, int N) {
    int wave_in_block = threadIdx.x >> 6;
    int lane = threadIdx.x & 63;
    int row = blockIdx.x * (blockDim.x >> 6) + wave_in_block;
    if (row >= N) return;
    const float2* zp = (const float2*)(z + (size_t)row * D);
    float2 v = zp[lane];
    float s = fabsf(v.x) + fabsf(v.y);
    #pragma unroll
    for (int m = 32; m >= 1; m >>= 1)
        s += __shfl_xor(s, m, 64);
    float inv = 1.0f / fmaxf(s, EPS);
    __half2* znp = (__half2*)(zn + (size_t)row * D);
    znp[lane] = __floats2half2_rn(v.x * inv, v.y * inv);
}

__global__ void transe_score_half_kernel(const __half* __restrict__ zn,
                                         const int* __restrict__ eidx,
                                         const int* __restrict__ etype,
                                         const float* __restrict__ rel,
                                         float* __restrict__ out, int E) {
    int gtid = blockIdx.x * blockDim.x + threadIdx.x;
    int e = gtid >> 4;
    int lane16 = threadIdx.x & 15;
    if (e >= E) return;

    int h = eidx[e];
    int t = eidx[E + e];
    int r = etype[e];

    float4 hraw = *(const float4*)(zn + (size_t)h * D + lane16 * 8);
    float4 traw = *(const float4*)(zn + (size_t)t * D + lane16 * 8);
    const float4* rp = (const float4*)(rel + (size_t)r * D) + lane16 * 2;
    float4 r0 = rp[0];
    float4 r1 = rp[1];

    const __half2* hh = (const __half2*)&hraw;
    const __half2* th = (const __half2*)&traw;
    float rf[8] = {r0.x, r0.y, r0.z, r0.w, r1.x, r1.y, r1.z, r1.w};

    float s = 0.0f;
    #pragma unroll
    for (int k = 0; k < 4; ++k) {
        float2 hf = __half22float2(hh[k]);
        float2 tf = __half22float2(th[k]);
        s += fabsf(hf.x + rf[2 * k]     - tf.x);
        s += fabsf(hf.y + rf[2 * k + 1] - tf.y);
    }
    s += __shfl_xor(s, 1, 64);
    s += __shfl_xor(s, 2, 64);
    s += __shfl_xor(s, 4, 64);
    s += __shfl_xor(s, 8, 64);
    if (lane16 == 0) out[e] = -s;
}

extern "C" void kernel_launch(void* const* d_in, const int* in_sizes, int n_in,
                              void* d_out, int out_size, void* d_ws, size_t ws_size,
                              hipStream_t stream) {
    const float* z    = (const float*)d_in[0];
    const int*   eidx = (const int*)d_in[1];
    const int*   etyp = (const int*)d_in[2];
    const float* rel  = (const float*)d_in[3];
    float* out = (float*)d_out;

    int N = in_sizes[0] / D;
    int E = in_sizes[2];
    int R = in_sizes[3] / D;

    size_t zn_bytes   = (size_t)N * D;                       // fp8 table, 12.8 MB
    size_t zn_aligned = (zn_bytes + 255) & ~(size_t)255;
    size_t relh_bytes = (size_t)R * D * sizeof(__half);      // fp16 rel, 128 KB
    size_t need_fp8   = zn_aligned + relh_bytes;

    if (ws_size >= need_fp8) {
        unsigned char* zn = (unsigned char*)d_ws;
        __half* relh = (__half*)((unsigned char*)d_ws + zn_aligned);
        int rows = N + R;
        int blocks1 = (rows + 7) / 8;                        // 8 rows / 256-thread block
        build_tables_kernel<<<blocks1, 256, 0, stream>>>(z, rel, zn, relh, N, R);
        int blocks2 = (E + 63) / 64;                         // 64 edges / 256-thread block
        transe_score_fp8_kernel<<<blocks2, 256, 0, stream>>>(zn, relh, eidx, etyp, out, E);
    } else {
        __half* zn = (__half*)d_ws;
        int blocks1 = (N + 3) / 4;
        normalize_to_half_kernel<<<blocks1, 256, 0, stream>>>(z, zn, N);
        int blocks2 = (E + 15) / 16;
        transe_score_half_kernel<<<blocks2, 256, 0, stream>>>(zn, eidx, etyp, rel, out, E);
    }
}

// Round 4
// 114.349 us; speedup vs baseline: 1.0512x; 1.0512x over previous
//
#include <hip/hip_runtime.h>
#include <hip/hip_fp16.h>

#define D 128
#define EPS 1e-12f
#define FP8_SCALE 64.0f
#define FP8_INV_SCALE 0.015625f

typedef float v2f __attribute__((ext_vector_type(2)));
typedef float v4f __attribute__((ext_vector_type(4)));   // native vector: OK for nontemporal builtins

// ---------- fp8-e4m3 table path ----------

// Pass 1 (one dispatch):
//   rows [0, N):    L1-normalize z row -> fp8 e4m3 (*64 scale), 128B/row
//   rows [N, N+R):  cast rel row fp32 -> fp16, 256B/row
// Plus: warm eidx/etype (6 MB) into L2/L3 — the 256 MiB workspace poison
// sweeps L3 every iteration, so without this the score kernel's dependency
// chain starts with a ~900-cycle HBM miss per edge.
__global__ void build_tables_kernel(const float* __restrict__ z,
                                    const float* __restrict__ rel,
                                    const uint4* __restrict__ eidx4,  // [2E/4]
                                    const uint4* __restrict__ etyp4,  // [E/4]
                                    int n_eidx4, int n_etyp4,
                                    unsigned char* __restrict__ zn,
                                    __half* __restrict__ relh,
                                    int N, int R) {
    int gtid = blockIdx.x * blockDim.x + threadIdx.x;

    // idx warm: read-and-keep-alive, no stores (rule-17 anti-DCE asm).
    if (gtid < n_eidx4) {
        uint4 w = eidx4[gtid];
        asm volatile("" :: "v"(w.x), "v"(w.y), "v"(w.z), "v"(w.w));
    }
    if (gtid < n_etyp4) {
        uint4 w = etyp4[gtid];
        asm volatile("" :: "v"(w.x), "v"(w.y), "v"(w.z), "v"(w.w));
    }

    int wave = threadIdx.x >> 6;
    int lane = threadIdx.x & 63;
    int rh   = lane >> 5;              // which of the wave's 2 rows
    int sub  = lane & 31;              // float4 index within the row
    int row  = blockIdx.x * ((blockDim.x >> 6) * 2) + wave * 2 + rh;

    if (row < N) {
        const v4f* zp = (const v4f*)(z + (size_t)row * D);
        v4f v = __builtin_nontemporal_load(zp + sub);      // z read once: don't pollute caches
        float s = fabsf(v.x) + fabsf(v.y) + fabsf(v.z) + fabsf(v.w);
        #pragma unroll
        for (int m = 16; m >= 1; m >>= 1)
            s += __shfl_xor(s, m, 64);                     // 5-step, within 32-lane half
        float f = FP8_SCALE / fmaxf(s, EPS);
        unsigned int p = __builtin_amdgcn_cvt_pk_fp8_f32(v.x * f, v.y * f, 0, false);
        p = __builtin_amdgcn_cvt_pk_fp8_f32(v.z * f, v.w * f, p, true);
        ((unsigned int*)(zn + (size_t)row * D))[sub] = p;  // 32 lanes x 4B = 128B row
    } else {
        int rr = row - N;
        if (rr < R) {
            const float4* rp = (const float4*)(rel + (size_t)rr * D);
            float4 v = rp[sub];
            float2 w;
            ((__half2*)&w)[0] = __floats2half2_rn(v.x, v.y);
            ((__half2*)&w)[1] = __floats2half2_rn(v.z, v.w);
            ((float2*)(relh + (size_t)rr * D))[sub] = w;   // 32 lanes x 8B = 256B row
        }
    }
}

// Pass 2: 8 lanes per edge (8 edges/wave) — proven R2 layout:
// 8 contiguous lanes cover one full 128B row per load instruction.
__global__ void transe_score_fp8_kernel(const unsigned char* __restrict__ zn,
                                        const __half* __restrict__ relh,
                                        const int* __restrict__ eidx,   // [2,E]
                                        const int* __restrict__ etype,  // [E]
                                        float* __restrict__ out, int E) {
    int gtid = blockIdx.x * blockDim.x + threadIdx.x;
    int e = gtid >> 3;
    int lane8 = threadIdx.x & 7;
    if (e >= E) return;

    int h = eidx[e];
    int t = eidx[E + e];
    int r = etype[e];

    uint4 hv = ((const uint4*)(zn + (size_t)h * D))[lane8];
    uint4 tv = ((const uint4*)(zn + (size_t)t * D))[lane8];
    const uint4* rp = (const uint4*)(relh + (size_t)r * D);
    uint4 rv0 = rp[lane8 * 2];
    uint4 rv1 = rp[lane8 * 2 + 1];

    unsigned int hw[4] = {hv.x, hv.y, hv.z, hv.w};
    unsigned int tw[4] = {tv.x, tv.y, tv.z, tv.w};
    unsigned int rw[8] = {rv0.x, rv0.y, rv0.z, rv0.w, rv1.x, rv1.y, rv1.z, rv1.w};

    float s = 0.0f;
    #pragma unroll
    for (int k = 0; k < 4; ++k) {
        v2f h0 = __builtin_amdgcn_cvt_pk_f32_fp8(hw[k], false);
        v2f h1 = __builtin_amdgcn_cvt_pk_f32_fp8(hw[k], true);
        v2f t0 = __builtin_amdgcn_cvt_pk_f32_fp8(tw[k], false);
        v2f t1 = __builtin_amdgcn_cvt_pk_f32_fp8(tw[k], true);
        float2 r0 = __half22float2(*(const __half2*)&rw[2 * k]);
        float2 r1 = __half22float2(*(const __half2*)&rw[2 * k + 1]);
        s += fabsf(fmaf(h0.x - t0.x, FP8_INV_SCALE, r0.x));
        s += fabsf(fmaf(h0.y - t0.y, FP8_INV_SCALE, r0.y));
        s += fabsf(fmaf(h1.x - t1.x, FP8_INV_SCALE, r1.x));
        s += fabsf(fmaf(h1.y - t1.y, FP8_INV_SCALE, r1.y));
    }
    s += __shfl_xor(s, 1, 64);
    s += __shfl_xor(s, 2, 64);
    s += __shfl_xor(s, 4, 64);
    if (lane8 == 0) __builtin_nontemporal_store(-s, out + e);
}

// ---------- fp16 fallback path (round-2, proven) ----------

__global__ void normalize_to_half_kernel(const float* __restrict__ z,
                                         __half* __restrict__ zn, int N) {
    int wave_in_block = threadIdx.x >> 6;
    int lane = threadIdx.x & 63;
    int row = blockIdx.x * (blockDim.x >> 6) + wave_in_block;
    if (row >= N) return;
    const float2* zp = (const float2*)(z + (size_t)row * D);
    float2 v = zp[lane];
    float s = fabsf(v.x) + fabsf(v.y);
    #pragma unroll
    for (int m = 32; m >= 1; m >>= 1)
        s += __shfl_xor(s, m, 64);
    float inv = 1.0f / fmaxf(s, EPS);
    __half2* znp = (__half2*)(zn + (size_t)row * D);
    znp[lane] = __floats2half2_rn(v.x * inv, v.y * inv);
}

__global__ void transe_score_half_kernel(const __half* __restrict__ zn,
                                         const int* __restrict__ eidx,
                                         const int* __restrict__ etype,
                                         const float* __restrict__ rel,
                                         float* __restrict__ out, int E) {
    int gtid = blockIdx.x * blockDim.x + threadIdx.x;
    int e = gtid >> 4;
    int lane16 = threadIdx.x & 15;
    if (e >= E) return;

    int h = eidx[e];
    int t = eidx[E + e];
    int r = etype[e];

    float4 hraw = *(const float4*)(zn + (size_t)h * D + lane16 * 8);
    float4 traw = *(const float4*)(zn + (size_t)t * D + lane16 * 8);
    const float4* rp = (const float4*)(rel + (size_t)r * D) + lane16 * 2;
    float4 r0 = rp[0];
    float4 r1 = rp[1];

    const __half2* hh = (const __half2*)&hraw;
    const __half2* th = (const __half2*)&traw;
    float rf[8] = {r0.x, r0.y, r0.z, r0.w, r1.x, r1.y, r1.z, r1.w};

    float s = 0.0f;
    #pragma unroll
    for (int k = 0; k < 4; ++k) {
        float2 hf = __half22float2(hh[k]);
        float2 tf = __half22float2(th[k]);
        s += fabsf(hf.x + rf[2 * k]     - tf.x);
        s += fabsf(hf.y + rf[2 * k + 1] - tf.y);
    }
    s += __shfl_xor(s, 1, 64);
    s += __shfl_xor(s, 2, 64);
    s += __shfl_xor(s, 4, 64);
    s += __shfl_xor(s, 8, 64);
    if (lane16 == 0) out[e] = -s;
}

extern "C" void kernel_launch(void* const* d_in, const int* in_sizes, int n_in,
                              void* d_out, int out_size, void* d_ws, size_t ws_size,
                              hipStream_t stream) {
    const float* z    = (const float*)d_in[0];
    const int*   eidx = (const int*)d_in[1];
    const int*   etyp = (const int*)d_in[2];
    const float* rel  = (const float*)d_in[3];
    float* out = (float*)d_out;

    int N = in_sizes[0] / D;
    int E = in_sizes[2];
    int R = in_sizes[3] / D;

    size_t zn_bytes   = (size_t)N * D;                       // fp8 table, 12.8 MB
    size_t zn_aligned = (zn_bytes + 255) & ~(size_t)255;
    size_t relh_bytes = (size_t)R * D * sizeof(__half);      // fp16 rel, 128 KB
    size_t need_fp8   = zn_aligned + relh_bytes;

    if (ws_size >= need_fp8) {
        unsigned char* zn = (unsigned char*)d_ws;
        __half* relh = (__half*)((unsigned char*)d_ws + zn_aligned);
        int rows = N + R;
        int blocks1 = (rows + 7) / 8;                        // 8 rows / 256-thread block
        int n_eidx4 = (2 * E) / 4;                           // eidx uint4 count (2E % 4 == 0 here)
        int n_etyp4 = E / 4;                                 // etype uint4 count
        build_tables_kernel<<<blocks1, 256, 0, stream>>>(z, rel,
                                                         (const uint4*)eidx,
                                                         (const uint4*)etyp,
                                                         n_eidx4, n_etyp4,
                                                         zn, relh, N, R);
        int blocks2 = (E + 31) / 32;                         // 32 edges / 256-thread block
        transe_score_fp8_kernel<<<blocks2, 256, 0, stream>>>(zn, relh, eidx, etyp, out, E);
    } else {
        __half* zn = (__half*)d_ws;
        int blocks1 = (N + 3) / 4;
        normalize_to_half_kernel<<<blocks1, 256, 0, stream>>>(z, zn, N);
        int blocks2 = (E + 15) / 16;
        transe_score_half_kernel<<<blocks2, 256, 0, stream>>>(zn, eidx, etyp, rel, out, E);
    }
}